// Round 6
// baseline (628.021 us; speedup 1.0000x reference)
//
#include <hip/hip_runtime.h>
#include <math.h>

// GBM path generator: S[:,0]=100; S[:,t] = 100 * exp(cumsum_{u=1..t}(A + VOL*(SQDT*Z[:,u])))
// A = (mean - vol^2/2)*dt (f32-rounded), VOL/SQDT pre-rounded to f32 separately
// to match the reference's rounding order: VOL * (SQDT * Z).
// One 64-lane wave per row of 366 columns; 366 = 61*6 so each lane owns a
// contiguous 6-column chunk (lanes 61..63 contribute zero). Segmented scan:
// lane-local 6-elem inclusive scan + 6-step shfl_up wave scan of lane totals.
// Grid-stride over row-groups with a capped grid (G11): 2048 blocks = 8/CU.

#define NCOLS 366
#define CH 6
#define ROWS_PER_BLOCK 4
#define GRID_BLOCKS 2048

__global__ __launch_bounds__(256, 8) void gbm_paths(const float* __restrict__ Z,
                                                    float* __restrict__ S,
                                                    int n_rows, int n_groups, float A,
                                                    float VOL, float SQDT) {
    const int lane = threadIdx.x & 63;
    const int waveInBlock = threadIdx.x >> 6;

    const int c0 = lane * CH;          // this lane's first column
    const bool active = (c0 < NCOLS);  // lanes 61..63 are out of range

    for (int grp = blockIdx.x; grp < n_groups; grp += GRID_BLOCKS) {
        const int row = grp * ROWS_PER_BLOCK + waveInBlock;
        if (row >= n_rows) continue;   // safety for non-multiple-of-4 row counts
        const long long base = (long long)row * NCOLS;
        const float* zrow = Z + base;
        float*       srow = S + base;

        // ---- load 6 log-returns (3x float2; byte addr = 24k -> 8B aligned) ----
        float r[CH];
        if (active) {
            const float2* p = reinterpret_cast<const float2*>(zrow + c0);
            float2 a0 = p[0], a1 = p[1], a2 = p[2];
            // match reference rounding: (SQDT*z) rounded, then VOL*that (+A fused)
            r[0] = fmaf(VOL, SQDT * a0.x, A);
            r[1] = fmaf(VOL, SQDT * a0.y, A);
            r[2] = fmaf(VOL, SQDT * a1.x, A);
            r[3] = fmaf(VOL, SQDT * a1.y, A);
            r[4] = fmaf(VOL, SQDT * a2.x, A);
            r[5] = fmaf(VOL, SQDT * a2.y, A);
            if (c0 == 0) r[0] = 0.0f;  // column 0: Z[:,0] unused, S[:,0]=S0 exactly
        } else {
            #pragma unroll
            for (int j = 0; j < CH; ++j) r[j] = 0.0f;
        }

        // ---- lane-local inclusive scan ----
        float incl[CH];
        float run = 0.0f;
        #pragma unroll
        for (int j = 0; j < CH; ++j) { run += r[j]; incl[j] = run; }

        // ---- wave-wide Kogge-Stone scan of lane totals (64 lanes, 6 steps) ----
        float x = run;
        #pragma unroll
        for (int d = 1; d < 64; d <<= 1) {
            float y = __shfl_up(x, d, 64);
            if (lane >= d) x += y;
        }
        const float excl = x - run;    // exclusive prefix of this lane's chunk

        // ---- exp + store (3x float2) ----
        if (active) {
            float s[CH];
            #pragma unroll
            for (int j = 0; j < CH; ++j) s[j] = 100.0f * expf(excl + incl[j]);
            float2* q = reinterpret_cast<float2*>(srow + c0);
            q[0] = make_float2(s[0], s[1]);
            q[1] = make_float2(s[2], s[3]);
            q[2] = make_float2(s[4], s[5]);
        }
    }
}

extern "C" void kernel_launch(void* const* d_in, const int* in_sizes, int n_in,
                              void* d_out, int out_size, void* d_ws, size_t ws_size,
                              hipStream_t stream) {
    const float* Z = (const float*)d_in[0];
    float*       S = (float*)d_out;
    const int n_rows = in_sizes[0] / NCOLS;
    const int n_groups = (n_rows + ROWS_PER_BLOCK - 1) / ROWS_PER_BLOCK;

    const double DT = 1.0 / 365.0;
    const float  A    = (float)((0.05 - 0.5 * 0.2 * 0.2) * DT);  // f32(drift*dt)
    const float  VOLf = 0.2f;
    const float  SQDT = (float)sqrt(DT);                         // f32(sqrt(dt))

    const int blocks = (GRID_BLOCKS < n_groups) ? GRID_BLOCKS : n_groups;
    gbm_paths<<<blocks, 256, 0, stream>>>(Z, S, n_rows, n_groups, A, VOLf, SQDT);
}

// Round 9
// 626.649 us; speedup vs baseline: 1.0022x; 1.0022x over previous
//
#include <hip/hip_runtime.h>
#include <math.h>

// GBM path generator: S[:,0]=100; S[:,t] = 100 * exp(cumsum_{u=1..t}(A + VOL*(SQDT*Z[:,u])))
// Coalesced lane-interleaved layout: row of 366 cols = 3 chunks {128,128,110}.
// Lane l owns columns {c*128 + 2l, c*128 + 2l + 1} -> every float2 load/store
// instruction covers a contiguous 512B span (fully-consumed cache lines).
// Row base is 8B-aligned (1464 % 8 == 0) so float2 is always legal (float4 is not).
// Scan: per chunk, lane pair-sum -> 6-step shfl_up wave scan -> chunk total via
// shfl(lane 63) carried into the next chunk. All 3 loads issued before scanning.

#define NCOLS 366
#define ROWS_PER_BLOCK 4
#define GRID_BLOCKS 2048

__global__ __launch_bounds__(256, 8) void gbm_paths(const float* __restrict__ Z,
                                                    float* __restrict__ S,
                                                    int n_rows, int n_groups, float A,
                                                    float VOL, float SQDT) {
    const int lane = threadIdx.x & 63;
    const int waveInBlock = threadIdx.x >> 6;

    // per-chunk column of this lane's pair
    const int col0 = 2 * lane;          // chunk 0: cols [0,128)
    const int col1 = 128 + 2 * lane;    // chunk 1: cols [128,256)
    const int col2 = 256 + 2 * lane;    // chunk 2: cols [256,366)
    const bool act2 = (col2 < NCOLS);   // lanes 0..54 active in chunk 2

    for (int grp = blockIdx.x; grp < n_groups; grp += GRID_BLOCKS) {
        const int row = grp * ROWS_PER_BLOCK + waveInBlock;
        if (row >= n_rows) continue;
        const long long base = (long long)row * NCOLS;
        const float* zrow = Z + base;
        float*       srow = S + base;

        // ---- issue all three coalesced float2 loads up front ----
        float2 z0 = *reinterpret_cast<const float2*>(zrow + col0);
        float2 z1 = *reinterpret_cast<const float2*>(zrow + col1);
        float2 z2 = act2 ? *reinterpret_cast<const float2*>(zrow + col2)
                         : make_float2(0.f, 0.f);

        // log-returns; reference rounding order: VOL * (SQDT * z) + A
        float r0a = fmaf(VOL, SQDT * z0.x, A);
        float r0b = fmaf(VOL, SQDT * z0.y, A);
        if (lane == 0) r0a = 0.0f;      // column 0: Z[:,0] unused, S[:,0]=S0
        float r1a = fmaf(VOL, SQDT * z1.x, A);
        float r1b = fmaf(VOL, SQDT * z1.y, A);
        float r2a = act2 ? fmaf(VOL, SQDT * z2.x, A) : 0.0f;
        float r2b = act2 ? fmaf(VOL, SQDT * z2.y, A) : 0.0f;

        float off = 0.0f;

        // ---- chunk 0 ----
        {
            const float pt = r0a + r0b;
            float x = pt;
            #pragma unroll
            for (int d = 1; d < 64; d <<= 1) {
                float y = __shfl_up(x, d, 64);
                if (lane >= d) x += y;
            }
            const float basev = off + (x - pt);
            float s0 = 100.0f * expf(basev + r0a);
            float s1 = 100.0f * expf(basev + pt);
            *reinterpret_cast<float2*>(srow + col0) = make_float2(s0, s1);
            off += __shfl(x, 63, 64);
        }
        // ---- chunk 1 ----
        {
            const float pt = r1a + r1b;
            float x = pt;
            #pragma unroll
            for (int d = 1; d < 64; d <<= 1) {
                float y = __shfl_up(x, d, 64);
                if (lane >= d) x += y;
            }
            const float basev = off + (x - pt);
            float s0 = 100.0f * expf(basev + r1a);
            float s1 = 100.0f * expf(basev + pt);
            *reinterpret_cast<float2*>(srow + col1) = make_float2(s0, s1);
            off += __shfl(x, 63, 64);
        }
        // ---- chunk 2 (110 cols; lanes 0..54) ----
        {
            const float pt = r2a + r2b;
            float x = pt;
            #pragma unroll
            for (int d = 1; d < 64; d <<= 1) {
                float y = __shfl_up(x, d, 64);
                if (lane >= d) x += y;
            }
            const float basev = off + (x - pt);
            if (act2) {
                float s0 = 100.0f * expf(basev + r2a);
                float s1 = 100.0f * expf(basev + pt);
                *reinterpret_cast<float2*>(srow + col2) = make_float2(s0, s1);
            }
        }
    }
}

extern "C" void kernel_launch(void* const* d_in, const int* in_sizes, int n_in,
                              void* d_out, int out_size, void* d_ws, size_t ws_size,
                              hipStream_t stream) {
    const float* Z = (const float*)d_in[0];
    float*       S = (float*)d_out;
    const int n_rows = in_sizes[0] / NCOLS;
    const int n_groups = (n_rows + ROWS_PER_BLOCK - 1) / ROWS_PER_BLOCK;

    const double DT = 1.0 / 365.0;
    const float  A    = (float)((0.05 - 0.5 * 0.2 * 0.2) * DT);  // f32(drift*dt)
    const float  VOLf = 0.2f;
    const float  SQDT = (float)sqrt(DT);                         // f32(sqrt(dt))

    const int blocks = (GRID_BLOCKS < n_groups) ? GRID_BLOCKS : n_groups;
    gbm_paths<<<blocks, 256, 0, stream>>>(Z, S, n_rows, n_groups, A, VOLf, SQDT);
}